// Round 16
// baseline (340.270 us; speedup 1.0000x reference)
//
#include <hip/hip_runtime.h>

#define NN 100000
#define EE 1600000
#define DD 128
#define NB 512        // buckets = nodes >> 8
#define CAP 4608      // bucket capacity (mean 4096 + 8 sigma)
#define CHUNK 8192    // edges per split block
#define SPLITB 196    // ceil(EE / CHUNK)

typedef __attribute__((ext_vector_type(8))) short short8v;          // MFMA A/B frag (8 bf16)
typedef __attribute__((ext_vector_type(4))) float f32x4;            // MFMA C/D frag
typedef __attribute__((ext_vector_type(8))) unsigned short ushort8v;

#define LROW 136      // LDS row stride in shorts (128 + 8 pad)

static __device__ __forceinline__ unsigned short f2bf(float x) {    // round-to-nearest-even
  unsigned u = __builtin_bit_cast(unsigned, x);
  return (unsigned short)((u + 0x7FFFu + ((u >> 16) & 1u)) >> 16);
}
static __device__ __forceinline__ float bf2f(unsigned short u) {
  return __builtin_bit_cast(float, (unsigned)u << 16);
}

// ---- init bucket cursors ----
__global__ __launch_bounds__(512) void initcur_k(int* __restrict__ cur_d,
                                                 int* __restrict__ cur_s) {
  int t = threadIdx.x;
  cur_d[t] = t * CAP;
  cur_s[t] = t * CAP;
}

// ---- pass 1 (merged): blocks [0,SPLITB) split edges into 512 buckets;
//      blocks [SPLITB, ...) do the fp32->bf16 conversions (independent work,
//      overlapped to hide the split's latency under the conv stream).
__global__ __launch_bounds__(256) void split_conv_k(const int* __restrict__ src,
                                                    const int* __restrict__ dst,
                                                    int* __restrict__ cur_d,
                                                    int* __restrict__ cur_s,
                                                    unsigned* __restrict__ tmp_d,
                                                    unsigned char* __restrict__ tmp_s,
                                                    const float* __restrict__ W1,
                                                    const float* __restrict__ W2,
                                                    const float* __restrict__ W3,
                                                    const float* __restrict__ feat,
                                                    unsigned short* __restrict__ Wbf,
                                                    unsigned short* __restrict__ vb1) {
  __shared__ int hd[NB], hs[NB], bd[NB], bs[NB];
  int t = threadIdx.x;

  if (blockIdx.x >= SPLITB) {
    // ---- conversion part ----
    int b = blockIdx.x - SPLITB;
    const float* srcp;
    unsigned short* dstp;
    int idx;
    if (b < 16)      { srcp = W1;   dstp = Wbf;         idx = b; }
    else if (b < 32) { srcp = W2;   dstp = Wbf + 16384; idx = b - 16; }
    else if (b < 48) { srcp = W3;   dstp = Wbf + 32768; idx = b - 32; }
    else             { srcp = feat; dstp = vb1;         idx = b - 48; }
    int i = idx * 256 + t;
    float4 v = *reinterpret_cast<const float4*>(srcp + i * 4);
    ushort4 pk = make_ushort4(f2bf(v.x), f2bf(v.y), f2bf(v.z), f2bf(v.w));
    *reinterpret_cast<ushort4*>(dstp + i * 4) = pk;
    return;
  }

  // ---- split part ----
  int base = blockIdx.x * CHUNK;
  int end = base + CHUNK < EE ? base + CHUNK : EE;
  for (int b = t; b < NB; b += 256) { hd[b] = 0; hs[b] = 0; }
  __syncthreads();
  for (int i = base + t; i < end; i += 256) {
    atomicAdd(&hd[dst[i] >> 8], 1);
    atomicAdd(&hs[src[i] >> 8], 1);
  }
  __syncthreads();
  for (int b = t; b < NB; b += 256) {
    bd[b] = hd[b] ? atomicAdd(&cur_d[b], hd[b]) : 0;
    bs[b] = hs[b] ? atomicAdd(&cur_s[b], hs[b]) : 0;
    hd[b] = 0;  // reuse as rank counters
    hs[b] = 0;
  }
  __syncthreads();
  for (int i = base + t; i < end; i += 256) {
    int s = src[i];
    int d = dst[i];
    int bin = d >> 8;
    int r = atomicAdd(&hd[bin], 1);
    int pos = bd[bin] + r;
    if (pos < (bin + 1) * CAP) tmp_d[pos] = ((unsigned)(d & 255) << 17) | (unsigned)s;
    bin = s >> 8;
    r = atomicAdd(&hs[bin], 1);
    pos = bs[bin] + r;
    if (pos < (bin + 1) * CAP) tmp_s[pos] = (unsigned char)(s & 255);
  }
}

// ---- pass 2 (merged): per-bucket dst counting sort -> CAP-strided csr + rows +
//      norm_in; src byte-histogram -> norm_out; AND within-bucket degree sort ->
//      perm (16-node groups become degree-uniform; bucket-local so epilogue
//      locality is preserved; dense since buckets are exact 256s, last = 160).
__global__ __launch_bounds__(256) void bucket_both_k(const unsigned* __restrict__ tmp_d,
                                                     const unsigned char* __restrict__ tmp_s,
                                                     const int* __restrict__ cur_d,
                                                     const int* __restrict__ cur_s,
                                                     int* __restrict__ csr,
                                                     int* __restrict__ row_s,
                                                     int* __restrict__ row_e,
                                                     float* __restrict__ norm_in,
                                                     float* __restrict__ norm_out,
                                                     int* __restrict__ perm) {
  __shared__ unsigned stage[CAP];
  __shared__ int h[256], sc[256], rk[256], h2[256];
  __shared__ int dh[64], dsc[64], drk[64];
  int b = blockIdx.x;
  int t = threadIdx.x;
  int cnt = cur_d[b] - b * CAP;
  cnt = cnt < CAP ? cnt : CAP;
  int cnts = cur_s[b] - b * CAP;
  cnts = cnts < CAP ? cnts : CAP;
  for (int i = t; i < cnt; i += 256) stage[i] = tmp_d[b * CAP + i];
  h[t] = 0;
  h2[t] = 0;
  if (t < 64) { dh[t] = 0; drk[t] = 0; }
  __syncthreads();
  const unsigned char* p = tmp_s + b * CAP;
  for (int i = t; i < cnts; i += 256) atomicAdd(&h2[p[i]], 1);
  for (int i = t; i < cnt; i += 256) atomicAdd(&h[stage[i] >> 17], 1);
  __syncthreads();
  int v = h[t];
  sc[t] = v;
  __syncthreads();
  int run = v;
  for (int off = 1; off < 256; off <<= 1) {
    int y = (t >= off) ? sc[t - off] : 0;
    __syncthreads();
    run += y;
    sc[t] = run;
    __syncthreads();
  }
  int excl = run - v;
  int n = b * 256 + t;
  bool valid = n < NN;
  if (valid) {
    row_s[n] = b * CAP + excl;
    row_e[n] = b * CAP + excl + v;
    norm_in[n] = rsqrtf((float)(v > 1 ? v : 1));
    norm_out[n] = rsqrtf((float)(h2[t] > 1 ? h2[t] : 1));
  }
  rk[t] = excl;
  // ---- degree histogram (64 bins, clamp) ----
  int dbin = v > 63 ? 63 : v;
  if (valid) atomicAdd(&dh[dbin], 1);
  __syncthreads();
  // csr scatter
  for (int i = t; i < cnt; i += 256) {
    unsigned w = stage[i];
    int r = atomicAdd(&rk[w >> 17], 1);
    csr[b * CAP + r] = (int)(w & 0x1FFFFu);
  }
  // scan 64 degree bins (first wave)
  if (t < 64) {
    int val = dh[t];
    int rn = val;
    for (int off = 1; off < 64; off <<= 1) {
      int y = __shfl_up(rn, off, 64);
      if (t >= off) rn += y;
    }
    dsc[t] = rn - val;
  }
  __syncthreads();
  if (valid) {
    int r = atomicAdd(&drk[dbin], 1);
    perm[b * 256 + dsc[dbin] + r] = n;
  }
}

// ---- fused layer (R13 gather structure + degree-uniform groups via perm):
// Block = 256 = 16 nodes (perm'd, ~equal degree), 16 lanes/node concurrent.
// Gather unroll x4 (16 rows in flight/wave) -> 4KB LDS tile -> swapped MFMA.
// mode 1: resid fp32 -> bf16 out; mode 3: resid bf16 -> bf16 out; mode 0: fp32 out.
__global__ __launch_bounds__(256) void layer_k(const unsigned short* __restrict__ h,
                                               const int* __restrict__ csr,
                                               const int* __restrict__ row_s,
                                               const int* __restrict__ row_e,
                                               const int* __restrict__ perm,
                                               const float* __restrict__ nsrc,
                                               const unsigned short* __restrict__ Wb,
                                               const float* __restrict__ bias,
                                               const float* __restrict__ nin,
                                               const float* __restrict__ residf,
                                               const unsigned short* __restrict__ residb,
                                               float* __restrict__ outf,
                                               unsigned short* __restrict__ outb,
                                               int mode) {
  __shared__ unsigned short tile[16 * LROW];  // 16 nodes x 128 cols bf16, +8 pad
  int t = threadIdx.x;
  int n16 = t >> 4;         // node slot within block
  int c = t & 15;           // 8-col chunk
  int bb = blockIdx.x * 16; // grid exact: 6250*16 == 100000
  int node = perm[bb + n16];

  // ---- gather phase: acc += v[src] * nout[src], unroll x4
  int e0 = row_s[node];
  int e1 = row_e[node];
  float acc[8] = {0.f, 0.f, 0.f, 0.f, 0.f, 0.f, 0.f, 0.f};
  const unsigned short* hb = h + c * 8;
  int e = e0;
  for (; e + 4 <= e1; e += 4) {
    int s0 = csr[e];
    int s1 = csr[e + 1];
    int s2 = csr[e + 2];
    int s3 = csr[e + 3];
    float n0 = nsrc[s0];
    float n1 = nsrc[s1];
    float n2 = nsrc[s2];
    float n3 = nsrc[s3];
    ushort8v u0 = *reinterpret_cast<const ushort8v*>(hb + (size_t)s0 * DD);
    ushort8v u1 = *reinterpret_cast<const ushort8v*>(hb + (size_t)s1 * DD);
    ushort8v u2 = *reinterpret_cast<const ushort8v*>(hb + (size_t)s2 * DD);
    ushort8v u3 = *reinterpret_cast<const ushort8v*>(hb + (size_t)s3 * DD);
#pragma unroll
    for (int i = 0; i < 8; ++i) {
      acc[i] += bf2f(u0[i]) * n0 + bf2f(u1[i]) * n1 +
                bf2f(u2[i]) * n2 + bf2f(u3[i]) * n3;
    }
  }
  for (; e < e1; ++e) {
    int s0 = csr[e];
    float n0 = nsrc[s0];
    ushort8v u = *reinterpret_cast<const ushort8v*>(hb + (size_t)s0 * DD);
#pragma unroll
    for (int i = 0; i < 8; ++i) acc[i] += bf2f(u[i]) * n0;
  }
  ushort8v o;
#pragma unroll
  for (int i = 0; i < 8; ++i) o[i] = f2bf(acc[i]);
  *reinterpret_cast<ushort8v*>(&tile[n16 * LROW + c * 8]) = o;
  __syncthreads();

  // ---- MFMA phase: wave w does col-tiles ct = 2w, 2w+1
  int wid = t >> 6;
  int lane = t & 63;
  int l15 = lane & 15;
  int kgrp = lane >> 4;

  const unsigned short* bp = &tile[l15 * LROW + kgrp * 8];
  short8v b0 = *reinterpret_cast<const short8v*>(bp);
  short8v b1 = *reinterpret_cast<const short8v*>(bp + 32);
  short8v b2 = *reinterpret_cast<const short8v*>(bp + 64);
  short8v b3 = *reinterpret_cast<const short8v*>(bp + 96);

  int epnode = perm[bb + l15];  // D col = tile row l15 -> perm'd node
  float ninv = nin[epnode];

#pragma unroll
  for (int q = 0; q < 2; ++q) {
    int ct = wid * 2 + q;
    const unsigned short* wp = Wb + (size_t)(ct * 16 + l15) * DD + kgrp * 8;
    short8v w0 = *reinterpret_cast<const short8v*>(wp);
    short8v w1 = *reinterpret_cast<const short8v*>(wp + 32);
    short8v w2 = *reinterpret_cast<const short8v*>(wp + 64);
    short8v w3 = *reinterpret_cast<const short8v*>(wp + 96);
    f32x4 cacc = {0.f, 0.f, 0.f, 0.f};
    cacc = __builtin_amdgcn_mfma_f32_16x16x32_bf16(w0, b0, cacc, 0, 0, 0);
    cacc = __builtin_amdgcn_mfma_f32_16x16x32_bf16(w1, b1, cacc, 0, 0, 0);
    cacc = __builtin_amdgcn_mfma_f32_16x16x32_bf16(w2, b2, cacc, 0, 0, 0);
    cacc = __builtin_amdgcn_mfma_f32_16x16x32_bf16(w3, b3, cacc, 0, 0, 0);

    int j = ct * 16 + kgrp * 4;
    float4 bj = *reinterpret_cast<const float4*>(bias + j);
    size_t idx = (size_t)epnode * DD + j;
    float4 v;
    v.x = (cacc[0] + bj.x) * ninv;
    v.y = (cacc[1] + bj.y) * ninv;
    v.z = (cacc[2] + bj.z) * ninv;
    v.w = (cacc[3] + bj.w) * ninv;
    if (mode == 1) {
      float4 rs = *reinterpret_cast<const float4*>(residf + idx);
      v.x = fmaxf(v.x + rs.x, 0.f);
      v.y = fmaxf(v.y + rs.y, 0.f);
      v.z = fmaxf(v.z + rs.z, 0.f);
      v.w = fmaxf(v.w + rs.w, 0.f);
      ushort4 hn = make_ushort4(f2bf(v.x), f2bf(v.y), f2bf(v.z), f2bf(v.w));
      *reinterpret_cast<ushort4*>(outb + idx) = hn;
    } else if (mode == 3) {
      ushort4 rs = *reinterpret_cast<const ushort4*>(residb + idx);
      v.x = fmaxf(v.x + bf2f(rs.x), 0.f);
      v.y = fmaxf(v.y + bf2f(rs.y), 0.f);
      v.z = fmaxf(v.z + bf2f(rs.z), 0.f);
      v.w = fmaxf(v.w + bf2f(rs.w), 0.f);
      ushort4 hn = make_ushort4(f2bf(v.x), f2bf(v.y), f2bf(v.z), f2bf(v.w));
      *reinterpret_cast<ushort4*>(outb + idx) = hn;
    } else {
      *reinterpret_cast<float4*>(outf + idx) = v;
    }
  }
}

extern "C" void kernel_launch(void* const* d_in, const int* in_sizes, int n_in,
                              void* d_out, int out_size, void* d_ws, size_t ws_size,
                              hipStream_t stream) {
  const float* feat = (const float*)d_in[0];
  const int* src = (const int*)d_in[1];
  const int* dst = (const int*)d_in[2];
  const float* W1 = (const float*)d_in[3];
  const float* b1 = (const float*)d_in[4];
  const float* W2 = (const float*)d_in[5];
  const float* b2 = (const float*)d_in[6];
  const float* W3 = (const float*)d_in[7];
  const float* b3 = (const float*)d_in[8];
  float* out = (float*)d_out;

  // ws layout (ints)
  int* row_s = (int*)d_ws;                   // N
  int* row_e = row_s + NN;                   // N
  float* norm_out = (float*)(row_e + NN);    // N
  float* norm_in = norm_out + NN;            // N
  int* perm = (int*)(norm_in + NN);          // N
  int* cur_d = perm + NN;                    // 512
  int* cur_s = cur_d + NB;                   // 512
  int* pad = cur_s + NB;                     // 512
  unsigned short* Wbf = (unsigned short*)pad;          // 3*16384 bf16 (24576 ints)
  int* csr = (int*)(Wbf + 3 * 16384);                  // NB*CAP ints (CAP-strided, 9.4MB)
  unsigned short* vb1 = (unsigned short*)(csr + NB * CAP);  // N*D bf16 (25.6MB)
  unsigned short* vb2 = vb1 + (size_t)NN * DD;              // N*D bf16 (ping-pong)

  // bucket temporaries live in d_out (dead before layer-3 writes it)
  unsigned* tmp_d = (unsigned*)d_out;                                   // 9.4MB
  unsigned char* tmp_s = (unsigned char*)d_out + (size_t)NB * CAP * 4;  // 2.4MB

  initcur_k<<<1, 512, 0, stream>>>(cur_d, cur_s);
  split_conv_k<<<SPLITB + 48 + 12500, 256, 0, stream>>>(src, dst, cur_d, cur_s, tmp_d,
                                                        tmp_s, W1, W2, W3, feat, Wbf, vb1);
  bucket_both_k<<<NB, 256, 0, stream>>>(tmp_d, tmp_s, cur_d, cur_s, csr, row_s, row_e,
                                        norm_in, norm_out, perm);

  // layer 1: gather vb1 (x nout), resid=feat fp32 -> vb2 (bf16)
  layer_k<<<6250, 256, 0, stream>>>(vb1, csr, row_s, row_e, perm, norm_out, Wbf, b1,
                                    norm_in, feat, nullptr, nullptr, vb2, 1);
  // layer 2: gather vb2 (x nout), resid=vb2 bf16 -> vb1 (bf16)
  layer_k<<<6250, 256, 0, stream>>>(vb2, csr, row_s, row_e, perm, norm_out, Wbf + 16384, b2,
                                    norm_in, nullptr, vb2, nullptr, vb1, 3);
  // layer 3: gather vb1 (x nout), no resid -> out fp32
  layer_k<<<6250, 256, 0, stream>>>(vb1, csr, row_s, row_e, perm, norm_out, Wbf + 32768, b3,
                                    norm_in, nullptr, nullptr, out, nullptr, 0);
}

// Round 17
// 311.384 us; speedup vs baseline: 1.0928x; 1.0928x over previous
//
#include <hip/hip_runtime.h>

#define NN 100000
#define EE 1600000
#define DD 128
#define NB 512        // buckets = nodes >> 8
#define CAP 4608      // bucket capacity (mean 4096 + 8 sigma)
#define CHUNK 8192    // edges per split block
#define SPLITB 196    // ceil(EE / CHUNK)

typedef __attribute__((ext_vector_type(8))) short short8v;          // MFMA A/B frag (8 bf16)
typedef __attribute__((ext_vector_type(4))) float f32x4;            // MFMA C/D frag
typedef __attribute__((ext_vector_type(8))) unsigned short ushort8v;

#define LROW 136      // LDS row stride in shorts (128 + 8 pad)

static __device__ __forceinline__ unsigned short f2bf(float x) {    // round-to-nearest-even
  unsigned u = __builtin_bit_cast(unsigned, x);
  return (unsigned short)((u + 0x7FFFu + ((u >> 16) & 1u)) >> 16);
}
static __device__ __forceinline__ float bf2f(unsigned short u) {
  return __builtin_bit_cast(float, (unsigned)u << 16);
}

// ---- init bucket cursors ----
__global__ __launch_bounds__(512) void initcur_k(int* __restrict__ cur_d,
                                                 int* __restrict__ cur_s) {
  int t = threadIdx.x;
  cur_d[t] = t * CAP;
  cur_s[t] = t * CAP;
}

// ---- pass 1 (merged): blocks [0,SPLITB) split edges into 512 buckets;
//      blocks [SPLITB, ...) do the fp32->bf16 conversions (independent work,
//      overlapped to hide the split's latency under the conv stream).
__global__ __launch_bounds__(256) void split_conv_k(const int* __restrict__ src,
                                                    const int* __restrict__ dst,
                                                    int* __restrict__ cur_d,
                                                    int* __restrict__ cur_s,
                                                    unsigned* __restrict__ tmp_d,
                                                    unsigned char* __restrict__ tmp_s,
                                                    const float* __restrict__ W1,
                                                    const float* __restrict__ W2,
                                                    const float* __restrict__ W3,
                                                    const float* __restrict__ feat,
                                                    unsigned short* __restrict__ Wbf,
                                                    unsigned short* __restrict__ vb1) {
  __shared__ int hd[NB], hs[NB], bd[NB], bs[NB];
  int t = threadIdx.x;

  if (blockIdx.x >= SPLITB) {
    // ---- conversion part ----
    int b = blockIdx.x - SPLITB;
    const float* srcp;
    unsigned short* dstp;
    int idx;
    if (b < 16)      { srcp = W1;   dstp = Wbf;         idx = b; }
    else if (b < 32) { srcp = W2;   dstp = Wbf + 16384; idx = b - 16; }
    else if (b < 48) { srcp = W3;   dstp = Wbf + 32768; idx = b - 32; }
    else             { srcp = feat; dstp = vb1;         idx = b - 48; }
    int i = idx * 256 + t;
    float4 v = *reinterpret_cast<const float4*>(srcp + i * 4);
    ushort4 pk = make_ushort4(f2bf(v.x), f2bf(v.y), f2bf(v.z), f2bf(v.w));
    *reinterpret_cast<ushort4*>(dstp + i * 4) = pk;
    return;
  }

  // ---- split part ----
  int base = blockIdx.x * CHUNK;
  int end = base + CHUNK < EE ? base + CHUNK : EE;
  for (int b = t; b < NB; b += 256) { hd[b] = 0; hs[b] = 0; }
  __syncthreads();
  for (int i = base + t; i < end; i += 256) {
    atomicAdd(&hd[dst[i] >> 8], 1);
    atomicAdd(&hs[src[i] >> 8], 1);
  }
  __syncthreads();
  for (int b = t; b < NB; b += 256) {
    bd[b] = hd[b] ? atomicAdd(&cur_d[b], hd[b]) : 0;
    bs[b] = hs[b] ? atomicAdd(&cur_s[b], hs[b]) : 0;
    hd[b] = 0;  // reuse as rank counters
    hs[b] = 0;
  }
  __syncthreads();
  for (int i = base + t; i < end; i += 256) {
    int s = src[i];
    int d = dst[i];
    int bin = d >> 8;
    int r = atomicAdd(&hd[bin], 1);
    int pos = bd[bin] + r;
    if (pos < (bin + 1) * CAP) tmp_d[pos] = ((unsigned)(d & 255) << 17) | (unsigned)s;
    bin = s >> 8;
    r = atomicAdd(&hs[bin], 1);
    pos = bs[bin] + r;
    if (pos < (bin + 1) * CAP) tmp_s[pos] = (unsigned char)(s & 255);
  }
}

// ---- pass 2 (merged): per-bucket dst counting sort -> CAP-strided csr + rows +
//      norm_in, AND src byte-histogram -> norm_out. csr row base = b*CAP + excl.
__global__ __launch_bounds__(256) void bucket_both_k(const unsigned* __restrict__ tmp_d,
                                                     const unsigned char* __restrict__ tmp_s,
                                                     const int* __restrict__ cur_d,
                                                     const int* __restrict__ cur_s,
                                                     int* __restrict__ csr,
                                                     int* __restrict__ row_s,
                                                     int* __restrict__ row_e,
                                                     float* __restrict__ norm_in,
                                                     float* __restrict__ norm_out) {
  __shared__ unsigned stage[CAP];
  __shared__ int h[256], sc[256], rk[256], h2[256];
  int b = blockIdx.x;
  int t = threadIdx.x;
  int cnt = cur_d[b] - b * CAP;
  cnt = cnt < CAP ? cnt : CAP;
  int cnts = cur_s[b] - b * CAP;
  cnts = cnts < CAP ? cnts : CAP;
  for (int i = t; i < cnt; i += 256) stage[i] = tmp_d[b * CAP + i];
  h[t] = 0;
  h2[t] = 0;
  __syncthreads();
  const unsigned char* p = tmp_s + b * CAP;
  for (int i = t; i < cnts; i += 256) atomicAdd(&h2[p[i]], 1);
  for (int i = t; i < cnt; i += 256) atomicAdd(&h[stage[i] >> 17], 1);
  __syncthreads();
  int v = h[t];
  sc[t] = v;
  __syncthreads();
  int run = v;
  for (int off = 1; off < 256; off <<= 1) {
    int y = (t >= off) ? sc[t - off] : 0;
    __syncthreads();
    run += y;
    sc[t] = run;
    __syncthreads();
  }
  int excl = run - v;
  int n = b * 256 + t;
  if (n < NN) {
    row_s[n] = b * CAP + excl;
    row_e[n] = b * CAP + excl + v;
    norm_in[n] = rsqrtf((float)(v > 1 ? v : 1));
    norm_out[n] = rsqrtf((float)(h2[t] > 1 ? h2[t] : 1));
  }
  rk[t] = excl;
  __syncthreads();
  for (int i = t; i < cnt; i += 256) {
    unsigned w = stage[i];
    int r = atomicAdd(&rk[w >> 17], 1);
    csr[b * CAP + r] = (int)(w & 0x1FFFFu);
  }
}

// ---- fused layer (R13 structure: gather unroll x4, 16 rows in flight/wave):
// Block = 256 = 16 nodes, 16 lanes/node concurrent (4 node-walks per wave).
// Then 4KB LDS tile -> swapped-operand MFMA.
// mode 1: resid fp32 -> bf16 out; mode 3: resid bf16 -> bf16 out; mode 0: fp32 out.
__global__ __launch_bounds__(256) void layer_k(const unsigned short* __restrict__ h,
                                               const int* __restrict__ csr,
                                               const int* __restrict__ row_s,
                                               const int* __restrict__ row_e,
                                               const float* __restrict__ nsrc,
                                               const unsigned short* __restrict__ Wb,
                                               const float* __restrict__ bias,
                                               const float* __restrict__ nin,
                                               const float* __restrict__ residf,
                                               const unsigned short* __restrict__ residb,
                                               float* __restrict__ outf,
                                               unsigned short* __restrict__ outb,
                                               int mode) {
  __shared__ unsigned short tile[16 * LROW];  // 16 nodes x 128 cols bf16, +8 pad
  int t = threadIdx.x;
  int n16 = t >> 4;         // node within block
  int c = t & 15;           // 8-col chunk
  int node = blockIdx.x * 16 + n16;  // grid exact: 6250*16 == 100000

  // ---- gather phase: acc += v[src] * nout[src], unroll x4
  int e0 = row_s[node];
  int e1 = row_e[node];
  float acc[8] = {0.f, 0.f, 0.f, 0.f, 0.f, 0.f, 0.f, 0.f};
  const unsigned short* hb = h + c * 8;
  int e = e0;
  for (; e + 4 <= e1; e += 4) {
    int s0 = csr[e];
    int s1 = csr[e + 1];
    int s2 = csr[e + 2];
    int s3 = csr[e + 3];
    float n0 = nsrc[s0];
    float n1 = nsrc[s1];
    float n2 = nsrc[s2];
    float n3 = nsrc[s3];
    ushort8v u0 = *reinterpret_cast<const ushort8v*>(hb + (size_t)s0 * DD);
    ushort8v u1 = *reinterpret_cast<const ushort8v*>(hb + (size_t)s1 * DD);
    ushort8v u2 = *reinterpret_cast<const ushort8v*>(hb + (size_t)s2 * DD);
    ushort8v u3 = *reinterpret_cast<const ushort8v*>(hb + (size_t)s3 * DD);
#pragma unroll
    for (int i = 0; i < 8; ++i) {
      acc[i] += bf2f(u0[i]) * n0 + bf2f(u1[i]) * n1 +
                bf2f(u2[i]) * n2 + bf2f(u3[i]) * n3;
    }
  }
  for (; e < e1; ++e) {
    int s0 = csr[e];
    float n0 = nsrc[s0];
    ushort8v u = *reinterpret_cast<const ushort8v*>(hb + (size_t)s0 * DD);
#pragma unroll
    for (int i = 0; i < 8; ++i) acc[i] += bf2f(u[i]) * n0;
  }
  ushort8v o;
#pragma unroll
  for (int i = 0; i < 8; ++i) o[i] = f2bf(acc[i]);
  *reinterpret_cast<ushort8v*>(&tile[n16 * LROW + c * 8]) = o;
  __syncthreads();

  // ---- MFMA phase: wave w does col-tiles ct = 2w, 2w+1
  int wid = t >> 6;
  int lane = t & 63;
  int l15 = lane & 15;
  int kgrp = lane >> 4;

  const unsigned short* bp = &tile[l15 * LROW + kgrp * 8];
  short8v b0 = *reinterpret_cast<const short8v*>(bp);
  short8v b1 = *reinterpret_cast<const short8v*>(bp + 32);
  short8v b2 = *reinterpret_cast<const short8v*>(bp + 64);
  short8v b3 = *reinterpret_cast<const short8v*>(bp + 96);

  int epnode = blockIdx.x * 16 + l15;  // D col = node (l15), D rows = out cols
  float ninv = nin[epnode];

#pragma unroll
  for (int q = 0; q < 2; ++q) {
    int ct = wid * 2 + q;
    const unsigned short* wp = Wb + (size_t)(ct * 16 + l15) * DD + kgrp * 8;
    short8v w0 = *reinterpret_cast<const short8v*>(wp);
    short8v w1 = *reinterpret_cast<const short8v*>(wp + 32);
    short8v w2 = *reinterpret_cast<const short8v*>(wp + 64);
    short8v w3 = *reinterpret_cast<const short8v*>(wp + 96);
    f32x4 cacc = {0.f, 0.f, 0.f, 0.f};
    cacc = __builtin_amdgcn_mfma_f32_16x16x32_bf16(w0, b0, cacc, 0, 0, 0);
    cacc = __builtin_amdgcn_mfma_f32_16x16x32_bf16(w1, b1, cacc, 0, 0, 0);
    cacc = __builtin_amdgcn_mfma_f32_16x16x32_bf16(w2, b2, cacc, 0, 0, 0);
    cacc = __builtin_amdgcn_mfma_f32_16x16x32_bf16(w3, b3, cacc, 0, 0, 0);

    int j = ct * 16 + kgrp * 4;
    float4 bj = *reinterpret_cast<const float4*>(bias + j);
    size_t idx = (size_t)epnode * DD + j;
    float4 v;
    v.x = (cacc[0] + bj.x) * ninv;
    v.y = (cacc[1] + bj.y) * ninv;
    v.z = (cacc[2] + bj.z) * ninv;
    v.w = (cacc[3] + bj.w) * ninv;
    if (mode == 1) {
      float4 rs = *reinterpret_cast<const float4*>(residf + idx);
      v.x = fmaxf(v.x + rs.x, 0.f);
      v.y = fmaxf(v.y + rs.y, 0.f);
      v.z = fmaxf(v.z + rs.z, 0.f);
      v.w = fmaxf(v.w + rs.w, 0.f);
      ushort4 hn = make_ushort4(f2bf(v.x), f2bf(v.y), f2bf(v.z), f2bf(v.w));
      *reinterpret_cast<ushort4*>(outb + idx) = hn;
    } else if (mode == 3) {
      ushort4 rs = *reinterpret_cast<const ushort4*>(residb + idx);
      v.x = fmaxf(v.x + bf2f(rs.x), 0.f);
      v.y = fmaxf(v.y + bf2f(rs.y), 0.f);
      v.z = fmaxf(v.z + bf2f(rs.z), 0.f);
      v.w = fmaxf(v.w + bf2f(rs.w), 0.f);
      ushort4 hn = make_ushort4(f2bf(v.x), f2bf(v.y), f2bf(v.z), f2bf(v.w));
      *reinterpret_cast<ushort4*>(outb + idx) = hn;
    } else {
      *reinterpret_cast<float4*>(outf + idx) = v;
    }
  }
}

extern "C" void kernel_launch(void* const* d_in, const int* in_sizes, int n_in,
                              void* d_out, int out_size, void* d_ws, size_t ws_size,
                              hipStream_t stream) {
  const float* feat = (const float*)d_in[0];
  const int* src = (const int*)d_in[1];
  const int* dst = (const int*)d_in[2];
  const float* W1 = (const float*)d_in[3];
  const float* b1 = (const float*)d_in[4];
  const float* W2 = (const float*)d_in[5];
  const float* b2 = (const float*)d_in[6];
  const float* W3 = (const float*)d_in[7];
  const float* b3 = (const float*)d_in[8];
  float* out = (float*)d_out;

  // ws layout (ints)
  int* row_s = (int*)d_ws;                   // N
  int* row_e = row_s + NN;                   // N
  float* norm_out = (float*)(row_e + NN);    // N
  float* norm_in = norm_out + NN;            // N
  int* cur_d = (int*)(norm_in + NN);         // 512
  int* cur_s = cur_d + NB;                   // 512
  int* pad = cur_s + NB;                     // 512
  unsigned short* Wbf = (unsigned short*)pad;          // 3*16384 bf16 (24576 ints)
  int* csr = (int*)(Wbf + 3 * 16384);                  // NB*CAP ints (CAP-strided, 9.4MB)
  unsigned short* vb1 = (unsigned short*)(csr + NB * CAP);  // N*D bf16 (25.6MB)
  unsigned short* vb2 = vb1 + (size_t)NN * DD;              // N*D bf16 (ping-pong)

  // bucket temporaries live in d_out (dead before layer-3 writes it)
  unsigned* tmp_d = (unsigned*)d_out;                                   // 9.4MB
  unsigned char* tmp_s = (unsigned char*)d_out + (size_t)NB * CAP * 4;  // 2.4MB

  initcur_k<<<1, 512, 0, stream>>>(cur_d, cur_s);
  split_conv_k<<<SPLITB + 48 + 12500, 256, 0, stream>>>(src, dst, cur_d, cur_s, tmp_d,
                                                        tmp_s, W1, W2, W3, feat, Wbf, vb1);
  bucket_both_k<<<NB, 256, 0, stream>>>(tmp_d, tmp_s, cur_d, cur_s, csr, row_s, row_e,
                                        norm_in, norm_out);

  // layer 1: gather vb1 (x nout), resid=feat fp32 -> vb2 (bf16)
  layer_k<<<6250, 256, 0, stream>>>(vb1, csr, row_s, row_e, norm_out, Wbf, b1,
                                    norm_in, feat, nullptr, nullptr, vb2, 1);
  // layer 2: gather vb2 (x nout), resid=vb2 bf16 -> vb1 (bf16)
  layer_k<<<6250, 256, 0, stream>>>(vb2, csr, row_s, row_e, norm_out, Wbf + 16384, b2,
                                    norm_in, nullptr, vb2, nullptr, vb1, 3);
  // layer 3: gather vb1 (x nout), no resid -> out fp32
  layer_k<<<6250, 256, 0, stream>>>(vb1, csr, row_s, row_e, norm_out, Wbf + 32768, b3,
                                    norm_in, nullptr, nullptr, out, nullptr, 0);
}